// Round 1
// baseline (593.508 us; speedup 1.0000x reference)
//
#include <hip/hip_runtime.h>
#include <hip/hip_bf16.h>

typedef __bf16 bf16;
typedef __attribute__((ext_vector_type(4))) __bf16 bf16x4;
typedef __attribute__((ext_vector_type(8))) __bf16 bf16x8;
typedef __attribute__((ext_vector_type(4))) float floatx4;

#define BB 16
#define NN 576
#define CC 768
#define HH 12
#define DH 64

// ---------------- convert fp32 -> bf16 (vectorized x4) ----------------
__global__ void k_convert(const float* __restrict__ in, bf16* __restrict__ out, int n4){
  int i = blockIdx.x*blockDim.x + threadIdx.x;
  if (i < n4){
    float4 f = ((const float4*)in)[i];
    bf16x4 o;
    o[0]=(bf16)f.x; o[1]=(bf16)f.y; o[2]=(bf16)f.z; o[3]=(bf16)f.w;
    ((bf16x4*)out)[i] = o;
  }
}

// ---------------- tiled transpose fp32[R][Cc] -> bf16[Cc][R] ----------------
__global__ void k_transpose(const float* __restrict__ src, bf16* __restrict__ dst, int R, int Cc){
  __shared__ float tile[32][33];
  int c0 = blockIdx.x*32, r0 = blockIdx.y*32;
  int tx = threadIdx.x & 31, ty = threadIdx.x >> 5;   // 32 x 8 threads
  #pragma unroll
  for (int i=0;i<4;i++)
    tile[ty + i*8][tx] = src[(size_t)(r0 + ty + i*8)*Cc + c0 + tx];
  __syncthreads();
  #pragma unroll
  for (int i=0;i<4;i++)
    dst[(size_t)(c0 + ty + i*8)*R + r0 + tx] = (bf16)tile[tx][ty + i*8];
}

// ---------------- positional softmax: pos[h][n][m], one wave per row ----------------
__global__ __launch_bounds__(256) void k_pos(const float* __restrict__ w_pos, float* __restrict__ pos){
  int t = threadIdx.x, wv = t>>6, lane = t&63;
  int rowid = blockIdx.x*4 + wv;           // [0, H*N)
  int h = rowid / NN, n = rowid % NN;
  float w0 = w_pos[h], w1 = w_pos[HH + h], w2 = w_pos[2*HH + h];
  int nx = n % 24, ny = n / 24;
  float e[9]; float mx = -1e30f;
  #pragma unroll
  for (int j=0;j<9;j++){
    int m = lane + 64*j;
    float dx = (float)(m % 24 - nx);
    float dy = (float)(m / 24 - ny);
    float l = dx*w0 + dy*w1 + (dx*dx + dy*dy)*w2;   // b_pos cancels in softmax
    e[j] = l; mx = fmaxf(mx, l);
  }
  #pragma unroll
  for (int s=1;s<64;s<<=1) mx = fmaxf(mx, __shfl_xor(mx, s, 64));
  float sum = 0.f;
  #pragma unroll
  for (int j=0;j<9;j++){ e[j] = __expf(e[j]-mx); sum += e[j]; }
  #pragma unroll
  for (int s=1;s<64;s<<=1) sum += __shfl_xor(sum, s, 64);
  float inv = 1.f/sum;
  float* dst = pos + (size_t)rowid*NN;
  #pragma unroll
  for (int j=0;j<9;j++) dst[lane + 64*j] = e[j]*inv;
}

// ---------------- shared MFMA mainloop: C[64x64] = A[M,K] @ Bt[N,K]^T ----------------
// 256 threads = 4 waves; wave w owns 16-col strip; acc[rt] = 16x16 tile rt (rows rt*16..)
// mfma_f32_16x16x32_bf16 layouts (HW-verified per guide):
//   A frag: lane m=lane&15, holds A[m][8q..8q+7], q=lane>>4
//   B frag: lane n=lane&15, holds B[8q+j][n]  == Bt[n][8q+j]
//   C/D:    col=lane&15, row=4*(lane>>4)+reg
__device__ __forceinline__ void gemm_main_bf16(
    const bf16* __restrict__ A, const bf16* __restrict__ Bt,
    int lda, int ldb, int K, int rowBase, int colBase,
    bf16 (*As)[40], bf16 (*Bs)[40], floatx4* acc)
{
  int t = threadIdx.x;
  int sr = t >> 2, scg = (t & 3) * 8;
  int wv = t >> 6, m16 = t & 15, q = (t & 63) >> 4;
  for (int k0 = 0; k0 < K; k0 += 32){
    *(bf16x8*)&As[sr][scg] = *(const bf16x8*)&A[(size_t)(rowBase + sr)*lda + k0 + scg];
    *(bf16x8*)&Bs[sr][scg] = *(const bf16x8*)&Bt[(size_t)(colBase + sr)*ldb + k0 + scg];
    __syncthreads();
    bf16x8 bfr = *(const bf16x8*)&Bs[wv*16 + m16][q*8];
    #pragma unroll
    for (int rt=0; rt<4; rt++){
      bf16x8 afr = *(const bf16x8*)&As[rt*16 + m16][q*8];
      acc[rt] = __builtin_amdgcn_mfma_f32_16x16x32_bf16(afr, bfr, acc[rt], 0, 0, 0);
    }
    __syncthreads();
  }
}

// same mainloop but A is fp32 (converted during staging)
__device__ __forceinline__ void gemm_main_f32A(
    const float* __restrict__ A, const bf16* __restrict__ Bt,
    int lda, int ldb, int K, int rowBase, int colBase,
    bf16 (*As)[40], bf16 (*Bs)[40], floatx4* acc)
{
  int t = threadIdx.x;
  int sr = t >> 2, scg = (t & 3) * 8;
  int wv = t >> 6, m16 = t & 15, q = (t & 63) >> 4;
  for (int k0 = 0; k0 < K; k0 += 32){
    float4 f0 = *(const float4*)&A[(size_t)(rowBase + sr)*lda + k0 + scg];
    float4 f1 = *(const float4*)&A[(size_t)(rowBase + sr)*lda + k0 + scg + 4];
    bf16x8 av;
    av[0]=(bf16)f0.x; av[1]=(bf16)f0.y; av[2]=(bf16)f0.z; av[3]=(bf16)f0.w;
    av[4]=(bf16)f1.x; av[5]=(bf16)f1.y; av[6]=(bf16)f1.z; av[7]=(bf16)f1.w;
    *(bf16x8*)&As[sr][scg] = av;
    *(bf16x8*)&Bs[sr][scg] = *(const bf16x8*)&Bt[(size_t)(colBase + sr)*ldb + k0 + scg];
    __syncthreads();
    bf16x8 bfr = *(const bf16x8*)&Bs[wv*16 + m16][q*8];
    #pragma unroll
    for (int rt=0; rt<4; rt++){
      bf16x8 afr = *(const bf16x8*)&As[rt*16 + m16][q*8];
      acc[rt] = __builtin_amdgcn_mfma_f32_16x16x32_bf16(afr, bfr, acc[rt], 0, 0, 0);
    }
    __syncthreads();
  }
}

// ---------------- GEMM1: x[9216,768] @ wcat[768,2304]; scatter epilogue ----------------
__global__ __launch_bounds__(256) void k_gemm1(
    const bf16* __restrict__ x_bf, const bf16* __restrict__ wcatT,
    bf16* __restrict__ q_bf, bf16* __restrict__ k_bf,
    bf16* __restrict__ vt_bf, float* __restrict__ v_out)
{
  __shared__ bf16 As[64][40];
  __shared__ bf16 Bs[64][40];
  int cb = blockIdx.x % 36, rb = blockIdx.x / 36;
  int rowBase = rb*64, colBase = cb*64;
  floatx4 acc[4] = {{0.f,0.f,0.f,0.f},{0.f,0.f,0.f,0.f},{0.f,0.f,0.f,0.f},{0.f,0.f,0.f,0.f}};
  gemm_main_bf16(x_bf, wcatT, CC, CC, CC, rowBase, colBase, As, Bs, acc);
  int wv = threadIdx.x >> 6, m16 = threadIdx.x & 15, q = (threadIdx.x & 63) >> 4;
  int col = colBase + wv*16 + m16;
  #pragma unroll
  for (int rt=0; rt<4; rt++){
    #pragma unroll
    for (int i=0;i<4;i++){
      int row = rowBase + rt*16 + q*4 + i;
      float val = acc[rt][i];
      int b = row / NN, n = row % NN;
      if (col < 2*CC){
        int s = col / CC, rem = col % CC;
        int h = rem >> 6, d = rem & 63;
        bf16* dst = s ? k_bf : q_bf;
        dst[(((b*HH + h)*NN + n) << 6) + d] = (bf16)val;
      } else {
        int rem = col - 2*CC;
        int h = rem >> 6, d = rem & 63;
        v_out[(((b*HH + h)*NN + n) << 6) + d] = val;              // output tuple elem 2
        vt_bf[((b*HH + h)*DH + d)*NN + n] = (bf16)val;            // V^T for PV gemm
      }
    }
  }
}

// ---------------- attention: scores (MFMA) + softmax + blend + renorm -> attn ----------------
__global__ __launch_bounds__(256) void k_attn(
    const bf16* __restrict__ q_bf, const bf16* __restrict__ k_bf,
    const float* __restrict__ pos, const float* __restrict__ gating,
    float* __restrict__ attn_out)
{
  __shared__ bf16 Qs[16][72];
  __shared__ bf16 Ks[64][72];
  __shared__ float S[16][592];
  int qt = blockIdx.x % 36, bh = blockIdx.x / 36;
  int h = bh % HH;
  int n0 = qt*16;
  int t = threadIdx.x;
  int wv = t>>6, m16 = t&15, q = (t&63)>>4;
  const bf16* Qg = q_bf + ((size_t)bh*NN + n0)*DH;
  const bf16* Kg = k_bf + (size_t)bh*NN*DH;
  { int r = t >> 4, c4 = (t & 15)*4;
    *(bf16x4*)&Qs[r][c4] = *(const bf16x4*)&Qg[r*DH + c4]; }
  for (int kt=0; kt<9; kt++){
    __syncthreads();   // also makes Qs visible on first iter; protects Ks reuse
    { int r = t>>2, cg = (t&3)*16;
      *(bf16x8*)&Ks[r][cg]   = *(const bf16x8*)&Kg[(kt*64 + r)*DH + cg];
      *(bf16x8*)&Ks[r][cg+8] = *(const bf16x8*)&Kg[(kt*64 + r)*DH + cg + 8]; }
    __syncthreads();
    floatx4 acc = {0.f,0.f,0.f,0.f};
    #pragma unroll
    for (int ks=0; ks<2; ks++){
      bf16x8 afr = *(const bf16x8*)&Qs[m16][ks*32 + q*8];
      bf16x8 bfr = *(const bf16x8*)&Ks[wv*16 + m16][ks*32 + q*8];
      acc = __builtin_amdgcn_mfma_f32_16x16x32_bf16(afr, bfr, acc, 0, 0, 0);
    }
    #pragma unroll
    for (int i=0;i<4;i++)
      S[q*4 + i][kt*64 + wv*16 + m16] = acc[i] * 0.125f;   // scale = Dh^-0.5
  }
  __syncthreads();
  // softmax over 576 keys: 16 threads per row
  int row = t >> 4, sub = t & 15;
  int n = n0 + row;
  float vals[36];
  float mx = -1e30f;
  #pragma unroll
  for (int j=0;j<36;j++){ float xv = S[row][sub + 16*j]; vals[j]=xv; mx = fmaxf(mx,xv); }
  #pragma unroll
  for (int s=1;s<16;s<<=1) mx = fmaxf(mx, __shfl_xor(mx, s, 64));
  float ps = 0.f;
  #pragma unroll
  for (int j=0;j<36;j++){ vals[j] = __expf(vals[j]-mx); ps += vals[j]; }
  #pragma unroll
  for (int s=1;s<16;s<<=1) ps += __shfl_xor(ps, s, 64);
  float g = 1.f/(1.f + __expf(-gating[h]));
  float ig = (1.f - g)/ps;
  const float* posrow = pos + ((size_t)h*NN + n)*NN;
  float bs = 0.f;
  #pragma unroll
  for (int j=0;j<36;j++){ float a = ig*vals[j] + g*posrow[sub + 16*j]; vals[j]=a; bs += a; }
  #pragma unroll
  for (int s=1;s<16;s<<=1) bs += __shfl_xor(bs, s, 64);
  float inv = 1.f/bs;   // == 1 mathematically; reference divides, we match
  float* arow = attn_out + ((size_t)bh*NN + n)*NN;
  #pragma unroll
  for (int j=0;j<36;j++) arow[sub + 16*j] = vals[j]*inv;
}

// ---------------- PV: out1[b,n,h*64+d] = attn[b,h,n,:] @ v[b,h,:,d] ----------------
__global__ __launch_bounds__(256) void k_pv(
    const float* __restrict__ attn, const bf16* __restrict__ vt_bf,
    bf16* __restrict__ out1_bf)
{
  __shared__ bf16 As[64][40];
  __shared__ bf16 Bs[64][40];
  int rb = blockIdx.x % 9, bh = blockIdx.x / 9;
  int b = bh / HH, h = bh % HH;
  const float* Ap = attn + (size_t)bh*NN*NN;
  const bf16* Bp = vt_bf + (size_t)bh*DH*NN;
  floatx4 acc[4] = {{0.f,0.f,0.f,0.f},{0.f,0.f,0.f,0.f},{0.f,0.f,0.f,0.f},{0.f,0.f,0.f,0.f}};
  gemm_main_f32A(Ap, Bp, NN, NN, NN, rb*64, 0, As, Bs, acc);
  int wv = threadIdx.x >> 6, m16 = threadIdx.x & 15, q = (threadIdx.x & 63) >> 4;
  int d = wv*16 + m16;
  #pragma unroll
  for (int rt=0; rt<4; rt++){
    #pragma unroll
    for (int i=0;i<4;i++){
      int n = rb*64 + rt*16 + q*4 + i;
      out1_bf[(size_t)(b*NN + n)*CC + h*DH + d] = (bf16)acc[rt][i];
    }
  }
}

// ---------------- projection: out = out1 @ w_proj + b_proj ----------------
__global__ __launch_bounds__(256) void k_proj(
    const bf16* __restrict__ out1_bf, const bf16* __restrict__ wprojT,
    const float* __restrict__ b_proj, float* __restrict__ out)
{
  __shared__ bf16 As[64][40];
  __shared__ bf16 Bs[64][40];
  int cb = blockIdx.x % 12, rb = blockIdx.x / 12;
  floatx4 acc[4] = {{0.f,0.f,0.f,0.f},{0.f,0.f,0.f,0.f},{0.f,0.f,0.f,0.f},{0.f,0.f,0.f,0.f}};
  gemm_main_bf16(out1_bf, wprojT, CC, CC, CC, rb*64, cb*64, As, Bs, acc);
  int wv = threadIdx.x >> 6, m16 = threadIdx.x & 15, q = (threadIdx.x & 63) >> 4;
  int col = cb*64 + wv*16 + m16;
  float bias = b_proj[col];
  #pragma unroll
  for (int rt=0; rt<4; rt++){
    #pragma unroll
    for (int i=0;i<4;i++){
      int row = rb*64 + rt*16 + q*4 + i;
      out[(size_t)row*CC + col] = acc[rt][i] + bias;
    }
  }
}

extern "C" void kernel_launch(void* const* d_in, const int* in_sizes, int n_in,
                              void* d_out, int out_size, void* d_ws, size_t ws_size,
                              hipStream_t stream)
{
  (void)in_sizes; (void)n_in; (void)out_size; (void)ws_size;
  const float* x      = (const float*)d_in[0];
  const float* w_qk   = (const float*)d_in[1];
  const float* w_v    = (const float*)d_in[2];
  const float* w_proj = (const float*)d_in[3];
  const float* b_proj = (const float*)d_in[4];
  const float* w_pos  = (const float*)d_in[5];
  // d_in[6] = b_pos: cancels in softmax, unused
  const float* gating = (const float*)d_in[7];

  float* out_ptr  = (float*)d_out;
  float* attn_ptr = out_ptr + (size_t)BB*NN*CC;        // 7,077,888
  float* v_ptr    = attn_ptr + (size_t)BB*HH*NN*NN;    // +63,700,992

  char* w = (char*)d_ws;
  bf16* x_bf    = (bf16*)(w);                 // 14,155,776 B  (reused as out1_bf after GEMM1/attn)
  bf16* wcatT   = (bf16*)(w + 14155776);      //  3,538,944 B  [2304][768]
  bf16* wprojT  = (bf16*)(w + 17694720);      //  1,179,648 B  [768][768]
  bf16* q_bf    = (bf16*)(w + 18874368);      // 14,155,776 B  [B,H,N,64]
  bf16* k_bf    = (bf16*)(w + 33030144);      // 14,155,776 B  [B,H,N,64]
  bf16* vt_bf   = (bf16*)(w + 47185920);      // 14,155,776 B  [B,H,64,N]
  float* pos    = (float*)(w + 61341696);     // 15,925,248 B  [H,N,N]
  bf16* out1_bf = x_bf;                       // alias: x_bf dead after k_gemm1

  k_convert<<<6912, 256, 0, stream>>>(x, x_bf, (BB*NN*CC)/4);
  k_transpose<<<dim3(48,24), 256, 0, stream>>>(w_qk, wcatT, CC, 2*CC);
  k_transpose<<<dim3(24,24), 256, 0, stream>>>(w_v, wcatT + (size_t)2*CC*CC, CC, CC);
  k_transpose<<<dim3(24,24), 256, 0, stream>>>(w_proj, wprojT, CC, CC);
  k_pos<<<(HH*NN)/4, 256, 0, stream>>>(w_pos, pos);
  k_gemm1<<<144*36, 256, 0, stream>>>(x_bf, wcatT, q_bf, k_bf, vt_bf, v_ptr);
  k_attn<<<192*36, 256, 0, stream>>>(q_bf, k_bf, pos, gating, attn_ptr);
  k_pv<<<192*9, 256, 0, stream>>>(attn_ptr, vt_bf, out1_bf);
  k_proj<<<144*12, 256, 0, stream>>>(out1_bf, wprojT, b_proj, out_ptr);
}

// Round 2
// 557.910 us; speedup vs baseline: 1.0638x; 1.0638x over previous
//
#include <hip/hip_runtime.h>
#include <hip/hip_bf16.h>

typedef __bf16 bf16;
typedef __attribute__((ext_vector_type(4))) __bf16 bf16x4;
typedef __attribute__((ext_vector_type(8))) __bf16 bf16x8;
typedef __attribute__((ext_vector_type(4))) float floatx4;

#define BB 16
#define NN 576
#define CC 768
#define HH 12
#define DH 64

// async global->LDS, 16B per lane; LDS dest = wave-uniform base + lane*16
#define GLOAD_LDS16(gp, lp) __builtin_amdgcn_global_load_lds( \
    (const __attribute__((address_space(1))) unsigned int*)(const void*)(gp), \
    (__attribute__((address_space(3))) unsigned int*)(void*)(lp), 16, 0, 0)

// ---------------- convert fp32 -> bf16 (vectorized x4) ----------------
__global__ void k_convert(const float* __restrict__ in, bf16* __restrict__ out, int n4){
  int i = blockIdx.x*blockDim.x + threadIdx.x;
  if (i < n4){
    float4 f = ((const float4*)in)[i];
    bf16x4 o;
    o[0]=(bf16)f.x; o[1]=(bf16)f.y; o[2]=(bf16)f.z; o[3]=(bf16)f.w;
    ((bf16x4*)out)[i] = o;
  }
}

// ---------------- tiled transpose fp32[R][Cc] -> bf16[Cc][R] ----------------
__global__ void k_transpose(const float* __restrict__ src, bf16* __restrict__ dst, int R, int Cc){
  __shared__ float tile[32][33];
  int c0 = blockIdx.x*32, r0 = blockIdx.y*32;
  int tx = threadIdx.x & 31, ty = threadIdx.x >> 5;   // 32 x 8 threads
  #pragma unroll
  for (int i=0;i<4;i++)
    tile[ty + i*8][tx] = src[(size_t)(r0 + ty + i*8)*Cc + c0 + tx];
  __syncthreads();
  #pragma unroll
  for (int i=0;i<4;i++)
    dst[(size_t)(c0 + ty + i*8)*R + r0 + tx] = (bf16)tile[tx][ty + i*8];
}

// ---------------- positional softmax: pos[h][n][m], one wave per row ----------------
__global__ __launch_bounds__(256) void k_pos(const float* __restrict__ w_pos, float* __restrict__ pos){
  int t = threadIdx.x, wv = t>>6, lane = t&63;
  int rowid = blockIdx.x*4 + wv;           // [0, H*N)
  int h = rowid / NN, n = rowid % NN;
  float w0 = w_pos[h], w1 = w_pos[HH + h], w2 = w_pos[2*HH + h];
  int nx = n % 24, ny = n / 24;
  float e[9]; float mx = -1e30f;
  #pragma unroll
  for (int j=0;j<9;j++){
    int m = lane + 64*j;
    float dx = (float)(m % 24 - nx);
    float dy = (float)(m / 24 - ny);
    float l = dx*w0 + dy*w1 + (dx*dx + dy*dy)*w2;   // b_pos cancels in softmax
    e[j] = l; mx = fmaxf(mx, l);
  }
  #pragma unroll
  for (int s=1;s<64;s<<=1) mx = fmaxf(mx, __shfl_xor(mx, s, 64));
  float sum = 0.f;
  #pragma unroll
  for (int j=0;j<9;j++){ e[j] = __expf(e[j]-mx); sum += e[j]; }
  #pragma unroll
  for (int s=1;s<64;s<<=1) sum += __shfl_xor(sum, s, 64);
  float inv = 1.f/sum;
  float* dst = pos + (size_t)rowid*NN;
  #pragma unroll
  for (int j=0;j<9;j++) dst[lane + 64*j] = e[j]*inv;
}

// ---------------- 128x128-tile MFMA mainloop (m97 structure) ----------------
// 256 threads = 4 waves in 2x2; wave quadrant 64x64 = 4x4 tiles of 16x16.
// As/Bs: [128][32] bf16 unpadded (required: global_load_lds writes base+lane*16).
// A frag: lane m=lane&15 holds A[m][8q..8q+7], q=lane>>4
// B frag: lane n=lane&15 holds Bt[n][8q..8q+7]
// C/D:    col=lane&15, row=4*(lane>>4)+reg
__device__ __forceinline__ void gemm128_main(
    const bf16* __restrict__ A, const bf16* __restrict__ B,
    int lda, int ldb, int K, bf16* As, bf16* Bs, floatx4 (*acc)[4])
{
  int t = threadIdx.x;
  int w = t>>6, m16 = t&15, q = (t&63)>>4;
  int wr = (w>>1)*64, wc = (w&1)*64;
  int sr = t>>2, kg = (t&3)*8;           // staging: slot t -> row t>>2, k-group t&3
  bf16* ldsA = As + w*512;               // wave-uniform LDS base (64 slots * 8 bf16)
  bf16* ldsB = Bs + w*512;
  for (int k0 = 0; k0 < K; k0 += 32){
    GLOAD_LDS16(A + (size_t)sr*lda      + k0 + kg, ldsA);
    GLOAD_LDS16(A + (size_t)(sr+64)*lda + k0 + kg, ldsA + 2048);
    GLOAD_LDS16(B + (size_t)sr*ldb      + k0 + kg, ldsB);
    GLOAD_LDS16(B + (size_t)(sr+64)*ldb + k0 + kg, ldsB + 2048);
    __syncthreads();                     // compiler emits vmcnt(0) drain before barrier
    bf16x8 af[4], bfv[4];
    #pragma unroll
    for (int rt=0;rt<4;rt++) af[rt]  = *(const bf16x8*)&As[(wr + rt*16 + m16)*32 + q*8];
    #pragma unroll
    for (int ct=0;ct<4;ct++) bfv[ct] = *(const bf16x8*)&Bs[(wc + ct*16 + m16)*32 + q*8];
    #pragma unroll
    for (int rt=0;rt<4;rt++)
      #pragma unroll
      for (int ct=0;ct<4;ct++)
        acc[rt][ct] = __builtin_amdgcn_mfma_f32_16x16x32_bf16(af[rt], bfv[ct], acc[rt][ct], 0, 0, 0);
    __syncthreads();
  }
}

// ---------------- GEMM1: x[9216,768] @ wcat[768,2304]; scatter epilogue ----------------
__global__ __launch_bounds__(256) void k_gemm1(
    const bf16* __restrict__ x_bf, const bf16* __restrict__ wcatT,
    bf16* __restrict__ q_bf, bf16* __restrict__ k_bf,
    bf16* __restrict__ vt_bf, float* __restrict__ v_out)
{
  __shared__ bf16 As[128*32];
  __shared__ bf16 Bs[128*32];
  int cb = blockIdx.x % 18, rb = blockIdx.x / 18;
  int rowBase = rb*128, colBase = cb*128;
  floatx4 zero = {0.f,0.f,0.f,0.f};
  floatx4 acc[4][4];
  #pragma unroll
  for (int a=0;a<4;a++)
    #pragma unroll
    for (int b=0;b<4;b++) acc[a][b] = zero;
  gemm128_main(x_bf + (size_t)rowBase*CC, wcatT + (size_t)colBase*CC, CC, CC, CC, As, Bs, acc);
  int t = threadIdx.x;
  int w = t>>6, m16 = t&15, q = (t&63)>>4;
  int wr = (w>>1)*64, wc = (w&1)*64;
  #pragma unroll
  for (int rt=0;rt<4;rt++){
    #pragma unroll
    for (int i=0;i<4;i++){
      int row = rowBase + wr + rt*16 + q*4 + i;
      int b = row / NN, n = row % NN;
      #pragma unroll
      for (int ct=0;ct<4;ct++){
        int col = colBase + wc + ct*16 + m16;
        float val = acc[rt][ct][i];
        if (col < 2*CC){
          int s = col / CC, rem = col % CC;
          int h = rem >> 6, d = rem & 63;
          bf16* dst = s ? k_bf : q_bf;
          dst[(((size_t)(b*HH + h)*NN + n) << 6) + d] = (bf16)val;
        } else {
          int rem = col - 2*CC;
          int h = rem >> 6, d = rem & 63;
          v_out[(((size_t)(b*HH + h)*NN + n) << 6) + d] = val;       // output tuple elem 2
          vt_bf[((size_t)(b*HH + h)*DH + d)*NN + n] = (bf16)val;     // V^T for fused PV
        }
      }
    }
  }
}

// ------- fused attention: scores (MFMA) + softmax + blend + renorm + attn write + PV -------
__global__ __launch_bounds__(256) void k_attn_pv(
    const bf16* __restrict__ q_bf, const bf16* __restrict__ k_bf,
    const bf16* __restrict__ vt_bf,
    const float* __restrict__ pos, const float* __restrict__ gating,
    float* __restrict__ attn_out, bf16* __restrict__ out1_bf)
{
  __shared__ bf16 Qs[16][72];
  __shared__ bf16 Ks[64][72];
  __shared__ float S[16][592];     // fp32 scores; later overlaid with bf16 P (A-frag source)
  int qt = blockIdx.x % 36, bh = blockIdx.x / 36;
  int b = bh / HH, h = bh % HH;
  int n0 = qt*16;
  int t = threadIdx.x;
  int wv = t>>6, m16 = t&15, q = (t&63)>>4;
  const bf16* Qg = q_bf + ((size_t)bh*NN + n0)*DH;
  const bf16* Kg = k_bf + (size_t)bh*NN*DH;
  { int r = t >> 4, c4 = (t & 15)*4;
    *(bf16x4*)&Qs[r][c4] = *(const bf16x4*)&Qg[r*DH + c4]; }
  for (int kt=0; kt<9; kt++){
    __syncthreads();   // Qs visible on first iter; protects Ks reuse after
    { int r = t>>2, cg = (t&3)*16;
      *(bf16x8*)&Ks[r][cg]   = *(const bf16x8*)&Kg[(kt*64 + r)*DH + cg];
      *(bf16x8*)&Ks[r][cg+8] = *(const bf16x8*)&Kg[(kt*64 + r)*DH + cg + 8]; }
    __syncthreads();
    floatx4 acc = {0.f,0.f,0.f,0.f};
    #pragma unroll
    for (int ks=0; ks<2; ks++){
      bf16x8 afr = *(const bf16x8*)&Qs[m16][ks*32 + q*8];
      bf16x8 bfr = *(const bf16x8*)&Ks[wv*16 + m16][ks*32 + q*8];
      acc = __builtin_amdgcn_mfma_f32_16x16x32_bf16(afr, bfr, acc, 0, 0, 0);
    }
    #pragma unroll
    for (int i=0;i<4;i++)
      S[q*4 + i][kt*64 + wv*16 + m16] = acc[i] * 0.125f;   // scale = Dh^-0.5
  }
  __syncthreads();
  // softmax over 576 keys: 16 threads per row
  int row = t >> 4, sub = t & 15;
  int n = n0 + row;
  float vals[36];
  float mx = -1e30f;
  #pragma unroll
  for (int j=0;j<36;j++){ float xv = S[row][sub + 16*j]; vals[j]=xv; mx = fmaxf(mx,xv); }
  #pragma unroll
  for (int s=1;s<16;s<<=1) mx = fmaxf(mx, __shfl_xor(mx, s, 64));
  float ps = 0.f;
  #pragma unroll
  for (int j=0;j<36;j++){ vals[j] = __expf(vals[j]-mx); ps += vals[j]; }
  #pragma unroll
  for (int s=1;s<16;s<<=1) ps += __shfl_xor(ps, s, 64);
  float g = 1.f/(1.f + __expf(-gating[h]));
  float ig = (1.f - g)/ps;
  const float* posrow = pos + ((size_t)h*NN + n)*NN;
  float bs = 0.f;
  #pragma unroll
  for (int j=0;j<36;j++){ float a = ig*vals[j] + g*posrow[sub + 16*j]; vals[j]=a; bs += a; }
  #pragma unroll
  for (int s=1;s<16;s<<=1) bs += __shfl_xor(bs, s, 64);
  float inv = 1.f/bs;   // == 1 mathematically; reference divides, we match
  __syncthreads();      // all S reads complete before P overlays it
  // write attn (fp32, HBM) + P (bf16 into S storage, row-swizzled +16B to spread banks)
  float* arow = attn_out + ((size_t)bh*NN + n)*NN;
  char* prow = (char*)(&S[0][0]) + row*2368 + ((row&3)<<4);
  #pragma unroll
  for (int j=0;j<36;j++){
    float a = vals[j]*inv;
    arow[sub + 16*j] = a;
    *(bf16*)(prow + 2*(sub + 16*j)) = (bf16)a;
  }
  __syncthreads();
  // PV: out1[16 x 64] = P[16,576] @ V[576,64]; B-frags straight from vt (L2-hot)
  floatx4 pacc = {0.f,0.f,0.f,0.f};
  const bf16* vrow = vt_bf + ((size_t)bh*DH + wv*16 + m16)*NN;
  const char* pbase = (const char*)(&S[0][0]) + m16*2368 + ((m16&3)<<4) + q*16;
  #pragma unroll
  for (int c=0;c<18;c++){
    bf16x8 afr = *(const bf16x8*)(pbase + c*64);
    bf16x8 bfr = *(const bf16x8*)&vrow[c*32 + q*8];
    pacc = __builtin_amdgcn_mfma_f32_16x16x32_bf16(afr, bfr, pacc, 0, 0, 0);
  }
  bf16* obase = out1_bf + ((size_t)(b*NN + n0))*CC + h*DH + wv*16 + m16;
  #pragma unroll
  for (int i=0;i<4;i++)
    obase[(size_t)(q*4 + i)*CC] = (bf16)pacc[i];
}

// ---------------- projection: out = out1 @ w_proj + b_proj ----------------
__global__ __launch_bounds__(256) void k_proj(
    const bf16* __restrict__ out1_bf, const bf16* __restrict__ wprojT,
    const float* __restrict__ b_proj, float* __restrict__ out)
{
  __shared__ bf16 As[128*32];
  __shared__ bf16 Bs[128*32];
  int cb = blockIdx.x % 6, rb = blockIdx.x / 6;
  int rowBase = rb*128, colBase = cb*128;
  floatx4 zero = {0.f,0.f,0.f,0.f};
  floatx4 acc[4][4];
  #pragma unroll
  for (int a=0;a<4;a++)
    #pragma unroll
    for (int b=0;b<4;b++) acc[a][b] = zero;
  gemm128_main(out1_bf + (size_t)rowBase*CC, wprojT + (size_t)colBase*CC, CC, CC, CC, As, Bs, acc);
  int t = threadIdx.x;
  int w = t>>6, m16 = t&15, q = (t&63)>>4;
  int wr = (w>>1)*64, wc = (w&1)*64;
  #pragma unroll
  for (int rt=0;rt<4;rt++){
    #pragma unroll
    for (int i=0;i<4;i++){
      int row = rowBase + wr + rt*16 + q*4 + i;
      #pragma unroll
      for (int ct=0;ct<4;ct++){
        int col = colBase + wc + ct*16 + m16;
        out[(size_t)row*CC + col] = acc[rt][ct][i] + b_proj[col];
      }
    }
  }
}

extern "C" void kernel_launch(void* const* d_in, const int* in_sizes, int n_in,
                              void* d_out, int out_size, void* d_ws, size_t ws_size,
                              hipStream_t stream)
{
  (void)in_sizes; (void)n_in; (void)out_size; (void)ws_size;
  const float* x      = (const float*)d_in[0];
  const float* w_qk   = (const float*)d_in[1];
  const float* w_v    = (const float*)d_in[2];
  const float* w_proj = (const float*)d_in[3];
  const float* b_proj = (const float*)d_in[4];
  const float* w_pos  = (const float*)d_in[5];
  // d_in[6] = b_pos: cancels in softmax, unused
  const float* gating = (const float*)d_in[7];

  float* out_ptr  = (float*)d_out;
  float* attn_ptr = out_ptr + (size_t)BB*NN*CC;        // 7,077,888
  float* v_ptr    = attn_ptr + (size_t)BB*HH*NN*NN;    // +63,700,992

  char* w = (char*)d_ws;
  bf16* x_bf    = (bf16*)(w);                 // 14,155,776 B  (reused as out1_bf)
  bf16* wcatT   = (bf16*)(w + 14155776);      //  3,538,944 B  [2304][768]
  bf16* wprojT  = (bf16*)(w + 17694720);      //  1,179,648 B  [768][768]
  bf16* q_bf    = (bf16*)(w + 18874368);      // 14,155,776 B  [B,H,N,64]
  bf16* k_bf    = (bf16*)(w + 33030144);      // 14,155,776 B  [B,H,N,64]
  bf16* vt_bf   = (bf16*)(w + 47185920);      // 14,155,776 B  [B,H,64,N]
  float* pos    = (float*)(w + 61341696);     // 15,925,248 B  [H,N,N]
  bf16* out1_bf = x_bf;                       // alias: x_bf dead after k_gemm1

  k_convert<<<6912, 256, 0, stream>>>(x, x_bf, (BB*NN*CC)/4);
  k_transpose<<<dim3(48,24), 256, 0, stream>>>(w_qk, wcatT, CC, 2*CC);
  k_transpose<<<dim3(24,24), 256, 0, stream>>>(w_v, wcatT + (size_t)2*CC*CC, CC, CC);
  k_transpose<<<dim3(24,24), 256, 0, stream>>>(w_proj, wprojT, CC, CC);
  k_pos<<<(HH*NN)/4, 256, 0, stream>>>(w_pos, pos);
  k_gemm1<<<72*18, 256, 0, stream>>>(x_bf, wcatT, q_bf, k_bf, vt_bf, v_ptr);
  k_attn_pv<<<192*36, 256, 0, stream>>>(q_bf, k_bf, vt_bf, pos, gating, attn_ptr, out1_bf);
  k_proj<<<72*6, 256, 0, stream>>>(out1_bf, wprojT, b_proj, out_ptr);
}

// Round 3
// 541.162 us; speedup vs baseline: 1.0967x; 1.0309x over previous
//
#include <hip/hip_runtime.h>
#include <hip/hip_bf16.h>

typedef __bf16 bf16;
typedef __attribute__((ext_vector_type(4))) __bf16 bf16x4;
typedef __attribute__((ext_vector_type(8))) __bf16 bf16x8;
typedef __attribute__((ext_vector_type(4))) float floatx4;

#define BB 16
#define NN 576
#define CC 768
#define HH 12
#define DH 64

// async global->LDS, 16B per lane; LDS dest = wave-uniform base + lane*16
#define GLOAD_LDS16(gp, lp) __builtin_amdgcn_global_load_lds( \
    (const __attribute__((address_space(1))) unsigned int*)(const void*)(gp), \
    (__attribute__((address_space(3))) unsigned int*)(void*)(lp), 16, 0, 0)

// ---------------- convert fp32 -> bf16 (vectorized x4) ----------------
__global__ void k_convert(const float* __restrict__ in, bf16* __restrict__ out, int n4){
  int i = blockIdx.x*blockDim.x + threadIdx.x;
  if (i < n4){
    float4 f = ((const float4*)in)[i];
    bf16x4 o;
    o[0]=(bf16)f.x; o[1]=(bf16)f.y; o[2]=(bf16)f.z; o[3]=(bf16)f.w;
    ((bf16x4*)out)[i] = o;
  }
}

// ---------------- tiled transpose fp32[R][Cc] -> bf16[Cc][R] ----------------
__global__ void k_transpose(const float* __restrict__ src, bf16* __restrict__ dst, int R, int Cc){
  __shared__ float tile[32][33];
  int c0 = blockIdx.x*32, r0 = blockIdx.y*32;
  int tx = threadIdx.x & 31, ty = threadIdx.x >> 5;   // 32 x 8 threads
  #pragma unroll
  for (int i=0;i<4;i++)
    tile[ty + i*8][tx] = src[(size_t)(r0 + ty + i*8)*Cc + c0 + tx];
  __syncthreads();
  #pragma unroll
  for (int i=0;i<4;i++)
    dst[(size_t)(c0 + ty + i*8)*R + r0 + tx] = (bf16)tile[tx][ty + i*8];
}

// ---------------- positional softmax: pos[h][n][m] -> bf16, one wave per row ----------------
__global__ __launch_bounds__(256) void k_pos(const float* __restrict__ w_pos, bf16* __restrict__ pos){
  int t = threadIdx.x, wv = t>>6, lane = t&63;
  int rowid = blockIdx.x*4 + wv;           // [0, H*N)
  int h = rowid / NN, n = rowid % NN;
  float w0 = w_pos[h], w1 = w_pos[HH + h], w2 = w_pos[2*HH + h];
  int nx = n % 24, ny = n / 24;
  float e[9]; float mx = -1e30f;
  #pragma unroll
  for (int j=0;j<9;j++){
    int m = lane + 64*j;
    float dx = (float)(m % 24 - nx);
    float dy = (float)(m / 24 - ny);
    float l = dx*w0 + dy*w1 + (dx*dx + dy*dy)*w2;   // b_pos cancels in softmax
    e[j] = l; mx = fmaxf(mx, l);
  }
  #pragma unroll
  for (int s=1;s<64;s<<=1) mx = fmaxf(mx, __shfl_xor(mx, s, 64));
  float sum = 0.f;
  #pragma unroll
  for (int j=0;j<9;j++){ e[j] = __expf(e[j]-mx); sum += e[j]; }
  #pragma unroll
  for (int s=1;s<64;s<<=1) sum += __shfl_xor(sum, s, 64);
  float inv = 1.f/sum;
  bf16* dst = pos + (size_t)rowid*NN;
  #pragma unroll
  for (int j=0;j<9;j++) dst[lane + 64*j] = (bf16)(e[j]*inv);
}

// ---------------- 128x128-tile MFMA mainloop (m97 structure) ----------------
__device__ __forceinline__ void gemm128_main(
    const bf16* __restrict__ A, const bf16* __restrict__ B,
    int lda, int ldb, int K, bf16* As, bf16* Bs, floatx4 (*acc)[4])
{
  int t = threadIdx.x;
  int w = t>>6, m16 = t&15, q = (t&63)>>4;
  int wr = (w>>1)*64, wc = (w&1)*64;
  int sr = t>>2, kg = (t&3)*8;           // staging: slot t -> row t>>2, k-group t&3
  bf16* ldsA = As + w*512;               // wave-uniform LDS base (64 slots * 8 bf16)
  bf16* ldsB = Bs + w*512;
  for (int k0 = 0; k0 < K; k0 += 32){
    GLOAD_LDS16(A + (size_t)sr*lda      + k0 + kg, ldsA);
    GLOAD_LDS16(A + (size_t)(sr+64)*lda + k0 + kg, ldsA + 2048);
    GLOAD_LDS16(B + (size_t)sr*ldb      + k0 + kg, ldsB);
    GLOAD_LDS16(B + (size_t)(sr+64)*ldb + k0 + kg, ldsB + 2048);
    __syncthreads();
    bf16x8 af[4], bfv[4];
    #pragma unroll
    for (int rt=0;rt<4;rt++) af[rt]  = *(const bf16x8*)&As[(wr + rt*16 + m16)*32 + q*8];
    #pragma unroll
    for (int ct=0;ct<4;ct++) bfv[ct] = *(const bf16x8*)&Bs[(wc + ct*16 + m16)*32 + q*8];
    #pragma unroll
    for (int rt=0;rt<4;rt++)
      #pragma unroll
      for (int ct=0;ct<4;ct++)
        acc[rt][ct] = __builtin_amdgcn_mfma_f32_16x16x32_bf16(af[rt], bfv[ct], acc[rt][ct], 0, 0, 0);
    __syncthreads();
  }
}

// ---------------- GEMM1: x[9216,768] @ wcat[768,2304]; scatter epilogue ----------------
// q gets pre-scaled by Dh^-0.5 = 0.125 so the attn kernel needs no score scaling.
__global__ __launch_bounds__(256) void k_gemm1(
    const bf16* __restrict__ x_bf, const bf16* __restrict__ wcatT,
    bf16* __restrict__ q_bf, bf16* __restrict__ k_bf,
    bf16* __restrict__ vt_bf, float* __restrict__ v_out)
{
  __shared__ bf16 As[128*32];
  __shared__ bf16 Bs[128*32];
  int cb = blockIdx.x % 18, rb = blockIdx.x / 18;
  int rowBase = rb*128, colBase = cb*128;
  floatx4 zero = {0.f,0.f,0.f,0.f};
  floatx4 acc[4][4];
  #pragma unroll
  for (int a=0;a<4;a++)
    #pragma unroll
    for (int b=0;b<4;b++) acc[a][b] = zero;
  gemm128_main(x_bf + (size_t)rowBase*CC, wcatT + (size_t)colBase*CC, CC, CC, CC, As, Bs, acc);
  int t = threadIdx.x;
  int w = t>>6, m16 = t&15, q = (t&63)>>4;
  int wr = (w>>1)*64, wc = (w&1)*64;
  #pragma unroll
  for (int rt=0;rt<4;rt++){
    #pragma unroll
    for (int i=0;i<4;i++){
      int row = rowBase + wr + rt*16 + q*4 + i;
      int b = row / NN, n = row % NN;
      #pragma unroll
      for (int ct=0;ct<4;ct++){
        int col = colBase + wc + ct*16 + m16;
        float val = acc[rt][ct][i];
        if (col < 2*CC){
          int s = col / CC, rem = col % CC;
          int h = rem >> 6, d = rem & 63;
          bf16* dst = s ? k_bf : q_bf;
          float sv = s ? val : val*0.125f;
          dst[(((size_t)(b*HH + h)*NN + n) << 6) + d] = (bf16)sv;
        } else {
          int rem = col - 2*CC;
          int h = rem >> 6, d = rem & 63;
          v_out[(((size_t)(b*HH + h)*NN + n) << 6) + d] = val;       // output tuple elem 2
          vt_bf[((size_t)(b*HH + h)*DH + d)*NN + n] = (bf16)val;     // V^T for fused PV
        }
      }
    }
  }
}

// ------- fused attention, 64 q-rows/block: scores in regs -> softmax in regs ->
//         blend(pos)+renorm -> attn write + P->LDS -> PV -> out1 -------
// LDS: K chunk staged (swizzled) in first 8 KB; after scores, same region becomes P[64][600] bf16.
__global__ __launch_bounds__(256, 2) void k_attn_pv(
    const bf16* __restrict__ q_bf, const bf16* __restrict__ k_bf,
    const bf16* __restrict__ vt_bf,
    const bf16* __restrict__ pos, const float* __restrict__ gating,
    float* __restrict__ attn_out, bf16* __restrict__ out1_bf)
{
  __shared__ __align__(16) char smem[64*1200];   // P[64][600] bf16; Ks aliased at offset 0
  int qt = blockIdx.x % 9, bh = blockIdx.x / 9;
  int b = bh / HH, h = bh % HH;
  int n0 = qt*64;
  int t = threadIdx.x;
  int wv = t>>6, m16 = t&15, q = (t&63)>>4;

  // Q A-frags: loaded once, reused for all 36 column tiles (q pre-scaled by 0.125 in gemm1)
  const bf16* qrow = q_bf + ((size_t)bh*NN + n0 + wv*16 + m16)*DH;
  bf16x8 afr0 = *(const bf16x8*)&qrow[q*8];
  bf16x8 afr1 = *(const bf16x8*)&qrow[32 + q*8];

  const bf16* Kg = k_bf + (size_t)bh*NN*DH;
  floatx4 acc[36];
  #pragma unroll
  for (int T=0;T<36;T++) acc[T] = (floatx4){0.f,0.f,0.f,0.f};

  // staging source with XOR-16B swizzle (dest is forced lane-linear by global_load_lds)
  int key0 = t>>3, g16 = (t&7) ^ (key0 & 7);
  #pragma unroll
  for (int kt=0; kt<9; kt++){
    __syncthreads();
    const bf16* src0 = Kg + (size_t)(kt*64 + key0)*DH + g16*8;
    GLOAD_LDS16(src0,           smem + wv*1024);
    GLOAD_LDS16(src0 + 32*DH,   smem + 4096 + wv*1024);
    __syncthreads();
    #pragma unroll
    for (int ct=0; ct<4; ct++){
      int key = ct*16 + m16;
      int swz = key & 7;
      bf16x8 b0 = *(const bf16x8*)(smem + key*128 + ((q ^ swz)<<4));
      bf16x8 b1 = *(const bf16x8*)(smem + key*128 + (((4 + q) ^ swz)<<4));
      acc[kt*4+ct] = __builtin_amdgcn_mfma_f32_16x16x32_bf16(afr0, b0, acc[kt*4+ct], 0, 0, 0);
      acc[kt*4+ct] = __builtin_amdgcn_mfma_f32_16x16x32_bf16(afr1, b1, acc[kt*4+ct], 0, 0, 0);
    }
  }

  // ---- softmax over 576 keys, fully in registers ----
  // C layout: lane col = m16 (within tile), rows = wv*16 + q*4 + i
  float mx[4], ps[4], bs[4];
  #pragma unroll
  for (int i=0;i<4;i++) mx[i] = -1e30f;
  #pragma unroll
  for (int T=0;T<36;T++)
    #pragma unroll
    for (int i=0;i<4;i++) mx[i] = fmaxf(mx[i], acc[T][i]);
  #pragma unroll
  for (int s=1;s<16;s<<=1)
    #pragma unroll
    for (int i=0;i<4;i++) mx[i] = fmaxf(mx[i], __shfl_xor(mx[i], s, 64));
  #pragma unroll
  for (int i=0;i<4;i++) ps[i] = 0.f;
  #pragma unroll
  for (int T=0;T<36;T++)
    #pragma unroll
    for (int i=0;i<4;i++){ float e = __expf(acc[T][i]-mx[i]); acc[T][i]=e; ps[i]+=e; }
  #pragma unroll
  for (int s=1;s<16;s<<=1)
    #pragma unroll
    for (int i=0;i<4;i++) ps[i] += __shfl_xor(ps[i], s, 64);

  float g = 1.f/(1.f + __expf(-gating[h]));
  float ig[4];
  #pragma unroll
  for (int i=0;i<4;i++){ ig[i] = (1.f-g)/ps[i]; bs[i] = 0.f; }

  // blend with positional softmax (bf16, LLC-resident)
  int rowq = n0 + wv*16 + q*4;                      // + i
  const bf16* posb = pos + ((size_t)h*NN + rowq)*NN + m16;
  #pragma unroll
  for (int T=0;T<36;T++)
    #pragma unroll
    for (int i=0;i<4;i++){
      float p = (float)posb[(size_t)i*NN + T*16];
      float a = ig[i]*acc[T][i] + g*p;
      acc[T][i] = a; bs[i] += a;
    }
  #pragma unroll
  for (int s=1;s<16;s<<=1)
    #pragma unroll
    for (int i=0;i<4;i++) bs[i] += __shfl_xor(bs[i], s, 64);
  float inv[4];
  #pragma unroll
  for (int i=0;i<4;i++) inv[i] = 1.f/bs[i];

  __syncthreads();   // all K-chunk reads done: P may overwrite the Ks region
  // write attn (fp32 output) + P (bf16 -> LDS, pitch 1200 B)
  float* arow = attn_out + ((size_t)bh*NN + rowq)*NN + m16;
  char* prow = smem + (size_t)(wv*16 + q*4)*1200 + m16*2;
  #pragma unroll
  for (int T=0;T<36;T++)
    #pragma unroll
    for (int i=0;i<4;i++){
      float a = acc[T][i]*inv[i];
      arow[(size_t)i*NN + T*16] = a;
      *(bf16*)(prow + i*1200 + T*32) = (bf16)a;
    }
  __syncthreads();

  // PV: O[64,64] = P[64,576] @ V[576,64]; each wave owns its 16 rows (A from own LDS strip),
  // B-frags straight from vt (L2-hot, shared across the 9 blocks of this bh)
  floatx4 pacc[4];
  #pragma unroll
  for (int ct=0;ct<4;ct++) pacc[ct] = (floatx4){0.f,0.f,0.f,0.f};
  const char* pbase = smem + (size_t)(wv*16 + m16)*1200 + q*16;
  const bf16* vbase = vt_bf + (size_t)bh*DH*NN + q*8;
  #pragma unroll
  for (int c=0;c<18;c++){
    bf16x8 afr = *(const bf16x8*)(pbase + c*64);
    #pragma unroll
    for (int ct=0;ct<4;ct++){
      bf16x8 bfr = *(const bf16x8*)&vbase[(size_t)(ct*16+m16)*NN + c*32];
      pacc[ct] = __builtin_amdgcn_mfma_f32_16x16x32_bf16(afr, bfr, pacc[ct], 0, 0, 0);
    }
  }
  bf16* obase = out1_bf + ((size_t)(b*NN + rowq))*CC + h*DH + m16;
  #pragma unroll
  for (int ct=0;ct<4;ct++)
    #pragma unroll
    for (int i=0;i<4;i++)
      obase[(size_t)i*CC + ct*16] = (bf16)pacc[ct][i];
}

// ---------------- projection: out = out1 @ w_proj + b_proj ----------------
__global__ __launch_bounds__(256) void k_proj(
    const bf16* __restrict__ out1_bf, const bf16* __restrict__ wprojT,
    const float* __restrict__ b_proj, float* __restrict__ out)
{
  __shared__ bf16 As[128*32];
  __shared__ bf16 Bs[128*32];
  int cb = blockIdx.x % 6, rb = blockIdx.x / 6;
  int rowBase = rb*128, colBase = cb*128;
  floatx4 zero = {0.f,0.f,0.f,0.f};
  floatx4 acc[4][4];
  #pragma unroll
  for (int a=0;a<4;a++)
    #pragma unroll
    for (int b=0;b<4;b++) acc[a][b] = zero;
  gemm128_main(out1_bf + (size_t)rowBase*CC, wprojT + (size_t)colBase*CC, CC, CC, CC, As, Bs, acc);
  int t = threadIdx.x;
  int w = t>>6, m16 = t&15, q = (t&63)>>4;
  int wr = (w>>1)*64, wc = (w&1)*64;
  #pragma unroll
  for (int rt=0;rt<4;rt++){
    #pragma unroll
    for (int i=0;i<4;i++){
      int row = rowBase + wr + rt*16 + q*4 + i;
      #pragma unroll
      for (int ct=0;ct<4;ct++){
        int col = colBase + wc + ct*16 + m16;
        out[(size_t)row*CC + col] = acc[rt][ct][i] + b_proj[col];
      }
    }
  }
}

extern "C" void kernel_launch(void* const* d_in, const int* in_sizes, int n_in,
                              void* d_out, int out_size, void* d_ws, size_t ws_size,
                              hipStream_t stream)
{
  (void)in_sizes; (void)n_in; (void)out_size; (void)ws_size;
  const float* x      = (const float*)d_in[0];
  const float* w_qk   = (const float*)d_in[1];
  const float* w_v    = (const float*)d_in[2];
  const float* w_proj = (const float*)d_in[3];
  const float* b_proj = (const float*)d_in[4];
  const float* w_pos  = (const float*)d_in[5];
  // d_in[6] = b_pos: cancels in softmax, unused
  const float* gating = (const float*)d_in[7];

  float* out_ptr  = (float*)d_out;
  float* attn_ptr = out_ptr + (size_t)BB*NN*CC;        // 7,077,888
  float* v_ptr    = attn_ptr + (size_t)BB*HH*NN*NN;    // +63,700,992

  char* w = (char*)d_ws;
  bf16* x_bf    = (bf16*)(w);                 // 14,155,776 B  (reused as out1_bf)
  bf16* wcatT   = (bf16*)(w + 14155776);      //  3,538,944 B  [2304][768]
  bf16* wprojT  = (bf16*)(w + 17694720);      //  1,179,648 B  [768][768]
  bf16* q_bf    = (bf16*)(w + 18874368);      // 14,155,776 B  [B,H,N,64]  (pre-scaled by 0.125)
  bf16* k_bf    = (bf16*)(w + 33030144);      // 14,155,776 B  [B,H,N,64]
  bf16* vt_bf   = (bf16*)(w + 47185920);      // 14,155,776 B  [B,H,64,N]
  bf16* pos_bf  = (bf16*)(w + 61341696);      //  7,962,624 B  [H,N,N] bf16
  bf16* out1_bf = x_bf;                       // alias: x_bf dead after k_gemm1

  k_convert<<<6912, 256, 0, stream>>>(x, x_bf, (BB*NN*CC)/4);
  k_transpose<<<dim3(48,24), 256, 0, stream>>>(w_qk, wcatT, CC, 2*CC);
  k_transpose<<<dim3(24,24), 256, 0, stream>>>(w_v, wcatT + (size_t)2*CC*CC, CC, CC);
  k_transpose<<<dim3(24,24), 256, 0, stream>>>(w_proj, wprojT, CC, CC);
  k_pos<<<(HH*NN)/4, 256, 0, stream>>>(w_pos, pos_bf);
  k_gemm1<<<72*18, 256, 0, stream>>>(x_bf, wcatT, q_bf, k_bf, vt_bf, v_ptr);
  k_attn_pv<<<192*9, 256, 0, stream>>>(q_bf, k_bf, vt_bf, pos_bf, gating, attn_ptr, out1_bf);
  k_proj<<<72*6, 256, 0, stream>>>(out1_bf, wprojT, b_proj, out_ptr);
}